// Round 1
// baseline (150.589 us; speedup 1.0000x reference)
//
#include <hip/hip_runtime.h>
#include <hip/hip_bf16.h>

typedef __attribute__((ext_vector_type(8))) short  short8;   // 8 bf16 in 4 VGPRs
typedef __attribute__((ext_vector_type(4))) float  f32x4;
typedef __attribute__((ext_vector_type(4))) unsigned short u16x4;
typedef __attribute__((ext_vector_type(2))) unsigned int  uint32x2;

#define WAITVM(n) asm volatile("s_waitcnt vmcnt(" #n ")" ::: "memory")

__device__ __forceinline__ unsigned short f2bf(float f) {
    union { float f; unsigned int u; } c; c.f = f;
    unsigned int u = c.u + 0x7FFFu + ((c.u >> 16) & 1u);   // RNE
    return (unsigned short)(u >> 16);
}

__device__ __forceinline__ unsigned int cvtpk_bf16(float lo, float hi) {
    unsigned int d;
    asm("v_cvt_pk_bf16_f32 %0, %1, %2" : "=v"(d) : "v"(lo), "v"(hi));
    return d;
}

__device__ __forceinline__ float exp2fast(float x) {
    float r;
    asm("v_exp_f32 %0, %1" : "=v"(r) : "v"(x));
    return r;
}

__device__ __forceinline__ void gll16(const void* g, void* lds) {
    __builtin_amdgcn_global_load_lds(
        (const __attribute__((address_space(1))) unsigned int*)g,
        (__attribute__((address_space(3))) unsigned int*)lds, 16, 0, 0);
}

// ---------------- fused prep: W transposes + x fp32->bf16 convert, one launch ----------------
__global__ void prep_kernel(const float* __restrict__ x, const float* __restrict__ Wq,
                            const float* __restrict__ Wp, unsigned short* __restrict__ xb,
                            unsigned short* __restrict__ WqT, unsigned short* __restrict__ WpT,
                            int nx) {
    const int blk = blockIdx.x;
    if (blk < 4096) {
        __shared__ float tile[32][33];
        const int cx = blk & 127;          // col-tile: 0..95 Wq, 96..127 Wp
        const int k0 = (blk >> 7) * 32;
        const float* W; unsigned short* Wt; int Nd, n0;
        if (cx < 96) { W = Wq; Wt = WqT; Nd = 3072; n0 = cx * 32; }
        else         { W = Wp; Wt = WpT; Nd = 1024; n0 = (cx - 96) * 32; }
        const int tx = threadIdx.x & 31, ty = threadIdx.x >> 5;   // 32x8
#pragma unroll
        for (int i = 0; i < 4; i++)
            tile[ty + i * 8][tx] = W[(size_t)(k0 + ty + i * 8) * Nd + n0 + tx];
        __syncthreads();
#pragma unroll
        for (int i = 0; i < 4; i++)
            Wt[(size_t)(n0 + ty + i * 8) * 1024 + k0 + tx] = f2bf(tile[tx][ty + i * 8]);
    } else {
        int i = ((blk - 4096) * 256 + threadIdx.x) * 4;
        if (i + 3 >= nx) return;
        float4 v = *(const float4*)(x + i);
        u16x4 o;
        o[0] = f2bf(v.x); o[1] = f2bf(v.y); o[2] = f2bf(v.z); o[3] = f2bf(v.w);
        *(u16x4*)(xb + i) = o;
    }
}

// =======================================================================================
// 8-phase 256x256x64 bf16 GEMM (m201-style: T2 swizzle + T3/T4 counted vmcnt + T5 setprio)
// 512 thr = 8 waves (2M x 4N), per-wave C = 128x64 (A rows wm*64+(mf&3)*16+(mf>>2)*128,
// B cols wn*16+nf*64). LDS 128 KiB = 2 K-tile buffers x (A 256x64 + B 256x64).
// Per iteration: 2 K-tiles, 8 phases; each phase = {ds_read subtile | 2x gll stage |
// barrier | lgkmcnt(0) | 16 MFMA} ; vmcnt(4) ONLY at phases 4 & 8 (drain-0 on last iter).
// Staging schedule (half-tile staged exactly >=1 barrier after its last ds_read):
//   ph1: buf1.A-h1(t1)  ph2: buf1.B-h1(t1)  ph3: buf0.A-h0(t2)  ph4: buf0.B-h0(t2)
//   ph5: buf0.A-h1(t2)  ph6: buf0.B-h1(t2)  ph7: buf1.A-h0(t3)  ph8: buf1.B-h0(t3)
// vmcnt(4)@ph4 -> landed through ph2 (covers all reads of ph5..8);
// vmcnt(4)@ph8 -> landed through ph6 (covers all reads of ph1..4 next iter). Verified.
// =======================================================================================
#define SA(b, ko, r) gll16(Asrc + (size_t)((r) * 64) * K + (ko), &lds[b][0][(r) * 4096 + w * 512])
#define SB(b, ko, r) gll16(Bsrc + (size_t)((r) * 64) * K + (ko), &lds[b][1][(r) * 4096 + w * 512])
#define BAR __builtin_amdgcn_s_barrier()
#define LGKM0 { asm volatile("s_waitcnt lgkmcnt(0)" ::: "memory"); __builtin_amdgcn_sched_barrier(0); }
#define LOADA(ab, MFG) { \
    _Pragma("unroll") \
    for (int m_ = 0; m_ < 4; m_++) { \
        af[m_][0] = *(const short8*)&(ab)[(MFG) * 8192 + arow + m_ * 1024 + pc0]; \
        af[m_][1] = *(const short8*)&(ab)[(MFG) * 8192 + arow + m_ * 1024 + pc1]; \
    } }
#define LOADB(dst, bb, NFG) { \
    _Pragma("unroll") \
    for (int n_ = 0; n_ < 2; n_++) { \
        dst[n_][0] = *(const short8*)&(bb)[((NFG) * 2 + n_) * 4096 + brow + pc0]; \
        dst[n_][1] = *(const short8*)&(bb)[((NFG) * 2 + n_) * 4096 + brow + pc1]; \
    } }
#define MMA(MFG, bv, NFG) { \
    __builtin_amdgcn_s_setprio(1); \
    _Pragma("unroll") \
    for (int m_ = 0; m_ < 4; m_++) \
        _Pragma("unroll") \
        for (int n_ = 0; n_ < 2; n_++) { \
            acc[(MFG) * 4 + m_][(NFG) * 2 + n_] = __builtin_amdgcn_mfma_f32_16x16x32_bf16( \
                af[m_][0], bv[n_][0], acc[(MFG) * 4 + m_][(NFG) * 2 + n_], 0, 0, 0); \
            acc[(MFG) * 4 + m_][(NFG) * 2 + n_] = __builtin_amdgcn_mfma_f32_16x16x32_bf16( \
                af[m_][1], bv[n_][1], acc[(MFG) * 4 + m_][(NFG) * 2 + n_], 0, 0, 0); \
        } \
    __builtin_amdgcn_s_setprio(0); }

template <int MODE>
__global__ __launch_bounds__(512, 2) void gemm256(
    const unsigned short* __restrict__ A,   // [M][K] bf16
    const unsigned short* __restrict__ Bt,  // [N][K] bf16
    const float* __restrict__ bias,
    float* __restrict__ Cf,
    unsigned short* __restrict__ kbuf,
    unsigned short* __restrict__ qbuf,
    unsigned short* __restrict__ vT,        // [1024][M]
    int M, int N, int K)
{
    __shared__ __align__(16) unsigned short lds[2][2][16384];  // [buf][A/B][256*64]

    const int tid = threadIdx.x;
    const int w = tid >> 6, lane = tid & 63;
    const int llo = lane & 15, lhi = lane >> 4;
    const int wm = w >> 2, wn = w & 3;

    const int nwg = gridDim.x * gridDim.y;
    const int bid = blockIdx.y * gridDim.x + blockIdx.x;
    const int wgid = (bid & 7) * (nwg >> 3) + (bid >> 3);
    const int mb = wgid / gridDim.x, nb = wgid - (wgid / gridDim.x) * gridDim.x;
    const int m0 = mb * 256, n0 = nb * 256;

    f32x4 acc[8][4];
#pragma unroll
    for (int m = 0; m < 8; m++)
#pragma unroll
        for (int n = 0; n < 4; n++)
#pragma unroll
            for (int r = 0; r < 4; r++) acc[m][n][r] = 0.0f;

    // staging source: thread tid covers row (tid>>3) of each 64-row block, chunk tid&7,
    // pre-swizzled global column so linear LDS dest + swizzled read are consistent
    const int tr = tid >> 3, tc = tid & 7;
    const int swz = (tc ^ (tr & 7)) * 8;
    const unsigned short* Asrc = A + (size_t)(m0 + tr) * K + swz;
    const unsigned short* Bsrc = Bt + (size_t)(n0 + tr) * K + swz;

    // prologue: tile0 (buf0) full 4 half-tiles, tile1 (buf1) A-h0 + B-h0
    SA(0, 0, 0); SA(0, 0, 1); SA(0, 0, 2); SA(0, 0, 3);
    SB(0, 0, 0); SB(0, 0, 1); SB(0, 0, 2); SB(0, 0, 3);
    SA(1, 64, 0); SA(1, 64, 1);
    SB(1, 64, 0); SB(1, 64, 1);
    WAITVM(4);                  // tile0 fully landed; tile1's 4 ops may fly
    BAR;

    const int kq = llo & 7;
    const int pc0 = (lhi ^ kq) * 8;        // swizzled chunk, ks=0
    const int pc1 = ((4 + lhi) ^ kq) * 8;  // ks=1
    const int arow = (wm * 64 + llo) * 64;
    const int brow = (wn * 16 + llo) * 64;

    const unsigned short* A0 = &lds[0][0][0];
    const unsigned short* B0 = &lds[0][1][0];
    const unsigned short* A1 = &lds[1][0][0];
    const unsigned short* B1 = &lds[1][1][0];

    short8 af[4][2], bf0[2][2], bf1[2][2];

    const int NIT = K >> 7;   // 8 iterations x 2 K-tiles
    for (int i = 0; i < NIT; ++i) {
        const int k1 = (2 * i + 1) * 64, k2 = (2 * i + 2) * 64, k3 = (2 * i + 3) * 64;
        const bool more = (i + 1 < NIT);

        // ---- ph1: buf0 (mf0-3 x nf0-1) ----
        LOADA(A0, 0); LOADB(bf0, B0, 0);
        SA(1, k1, 2); SA(1, k1, 3);
        BAR; LGKM0; MMA(0, bf0, 0); BAR;
        // ---- ph2: buf0 (mf0-3 x nf2-3) ----
        LOADB(bf1, B0, 1);
        SB(1, k1, 2); SB(1, k1, 3);
        BAR; LGKM0; MMA(0, bf1, 1); BAR;
        // ---- ph3: buf0 (mf4-7 x nf0-1) ----
        LOADA(A0, 1);
        if (more) { SA(0, k2, 0); SA(0, k2, 1); }
        BAR; LGKM0; MMA(1, bf0, 0); BAR;
        // ---- ph4: buf0 (mf4-7 x nf2-3) + counted wait ----
        if (more) { SB(0, k2, 0); SB(0, k2, 1); WAITVM(4); } else { WAITVM(0); }
        BAR; LGKM0; MMA(1, bf1, 1); BAR;
        // ---- ph5: buf1 (mf0-3 x nf0-1) ----
        LOADA(A1, 0); LOADB(bf0, B1, 0);
        if (more) { SA(0, k2, 2); SA(0, k2, 3); }
        BAR; LGKM0; MMA(0, bf0, 0); BAR;
        // ---- ph6: buf1 (mf0-3 x nf2-3) ----
        LOADB(bf1, B1, 1);
        if (more) { SB(0, k2, 2); SB(0, k2, 3); }
        BAR; LGKM0; MMA(0, bf1, 1); BAR;
        // ---- ph7: buf1 (mf4-7 x nf0-1) ----
        LOADA(A1, 1);
        if (more) { SA(1, k3, 0); SA(1, k3, 1); }
        BAR; LGKM0; MMA(1, bf0, 0); BAR;
        // ---- ph8: buf1 (mf4-7 x nf2-3) + counted wait ----
        if (more) { SB(1, k3, 0); SB(1, k3, 1); WAITVM(4); }
        BAR; LGKM0; MMA(1, bf1, 1); BAR;
    }

    if constexpr (MODE == 0) {
#pragma unroll
        for (int nf = 0; nf < 4; nf++) {
            const int col = n0 + wn * 16 + nf * 64 + llo;
            const float bb = bias[col];
#pragma unroll
            for (int mf = 0; mf < 8; mf++) {
                const int row0 = m0 + wm * 64 + (mf & 3) * 16 + (mf >> 2) * 128 + lhi * 4;
#pragma unroll
                for (int r = 0; r < 4; r++)
                    Cf[(size_t)(row0 + r) * N + col] = acc[mf][nf][r] + bb;
            }
        }
    } else {
        // QKV split: thirds are 1024-wide, frags 16-aligned -> `third` wave-uniform per nf
#pragma unroll
        for (int nf = 0; nf < 4; nf++) {
            const int col = n0 + wn * 16 + nf * 64 + llo;
            const int third = col >> 10;
            const int cl = col & 1023;
            const float bb = bias[col];
            if (third == 2) {
#pragma unroll
                for (int mf = 0; mf < 8; mf++) {
                    const int row0 = m0 + wm * 64 + (mf & 3) * 16 + (mf >> 2) * 128 + lhi * 4;
                    u16x4 pk;
#pragma unroll
                    for (int r = 0; r < 4; r++) pk[r] = f2bf(acc[mf][nf][r] + bb);
                    *(u16x4*)&vT[(size_t)cl * M + row0] = pk;
                }
            } else {
                unsigned short* dst = (third == 0) ? kbuf : qbuf;
                const float sc = (third == 1) ? 0.18033688f : 1.0f;  // 0.125*log2e
#pragma unroll
                for (int mf = 0; mf < 8; mf++) {
                    const int row0 = m0 + wm * 64 + (mf & 3) * 16 + (mf >> 2) * 128 + lhi * 4;
#pragma unroll
                    for (int r = 0; r < 4; r++)
                        dst[(size_t)(row0 + r) * 1024 + cl] = f2bf((acc[mf][nf][r] + bb) * sc);
                }
            }
        }
    }
}

#undef SA
#undef SB
#undef LOADA
#undef LOADB
#undef MMA
#undef BAR
#undef LGKM0

// ---------------- bf16 MFMA GEMM: BM=128, BN=128, BK=64 (proven; used for proj) ----------------
template <int BN, int MODE, int NT>
__global__ __launch_bounds__(512, 4) void gemmk64(
    const unsigned short* __restrict__ A,   // [M][K] bf16
    const unsigned short* __restrict__ Bt,  // [N][K] bf16
    const float* __restrict__ bias,
    float* __restrict__ Cf,
    unsigned short* __restrict__ kbuf,
    unsigned short* __restrict__ qbuf,
    unsigned short* __restrict__ vT,        // [1024][M]
    int M, int N, int K)
{
    constexpr int NF = BN / 64;
    constexpr int ABASE = 128 * 64;
    constexpr int SLOT = (128 + BN) * 64;
    __shared__ __align__(16) unsigned short lds[2][SLOT];

    const int tid = threadIdx.x;
    const int w = tid >> 6, lane = tid & 63;
    const int llo = lane & 15, lhi = lane >> 4;
    const int wm = w >> 2, wn = w & 3;

    const int nwg = gridDim.x * gridDim.y;
    const int bid = blockIdx.y * gridDim.x + blockIdx.x;
    const int wgid = (bid & 7) * (nwg >> 3) + (bid >> 3);
    const int mb = wgid / gridDim.x, nb = wgid - (wgid / gridDim.x) * gridDim.x;
    const int m0 = mb * 128, n0 = nb * BN;

    f32x4 acc[4][NF];
#pragma unroll
    for (int m = 0; m < 4; m++)
#pragma unroll
        for (int n = 0; n < NF; n++)
#pragma unroll
            for (int r = 0; r < 4; r++) acc[m][n][r] = 0.0f;

    const int gr8 = lane >> 3;
    const int swc = ((lane & 7) ^ gr8) * 8;
    const unsigned short* Asrc = A  + (size_t)(m0 + w * 16 + gr8) * K + swc;
    const unsigned short* Bsrc = Bt + (size_t)(n0 + w * 8 * NF + gr8) * K + swc;

    auto STAGE = [&](int sl_, int kt_) {
        unsigned short* sl = &lds[sl_][0];
        const size_t ko = (size_t)kt_ * 64;
        gll16(Asrc + ko,                 sl + (w * 16) * 64);
        gll16(Asrc + ko + 8 * (size_t)K, sl + (w * 16 + 8) * 64);
#pragma unroll
        for (int u = 0; u < NF; u++)
            gll16(Bsrc + ko + (size_t)(8 * u) * K, sl + ABASE + (w * 8 * NF + 8 * u) * 64);
    };

    STAGE(0, 0);

    const int sk = llo & 7;
    const int arow = (wm * 64 + llo) * 64;
    const int brow = ABASE + (wn * 16 * NF + llo) * 64;

    for (int kt = 0; kt < NT; ++kt) {
        WAITVM(0);                             // own tile-kt loads landed
        __builtin_amdgcn_s_barrier();          // all waves: kt published; kt-1 reads done
        __builtin_amdgcn_sched_barrier(0);

        if (kt + 1 < NT) STAGE((kt + 1) & 1, kt + 1);   // into slot read at kt-1

        const unsigned short* sa = &lds[kt & 1][0];

#pragma unroll
        for (int ks = 0; ks < 2; ks++) {
            const int pc = ((ks * 4 + lhi) ^ sk) * 8;
            short8 af[4], bv[NF];
#pragma unroll
            for (int m = 0; m < 4; m++) af[m] = *(const short8*)&sa[arow + m * 1024 + pc];
#pragma unroll
            for (int n = 0; n < NF; n++) bv[n] = *(const short8*)&sa[brow + n * 1024 + pc];

            __builtin_amdgcn_s_setprio(1);
#pragma unroll
            for (int m = 0; m < 4; m++)
#pragma unroll
                for (int n = 0; n < NF; n++)
                    acc[m][n] = __builtin_amdgcn_mfma_f32_16x16x32_bf16(af[m], bv[n], acc[m][n], 0, 0, 0);
            __builtin_amdgcn_s_setprio(0);
        }
    }

    if constexpr (MODE == 0) {
#pragma unroll
        for (int n = 0; n < NF; n++) {
            int col = n0 + wn * 16 * NF + n * 16 + llo;
            float bb = bias[col];
#pragma unroll
            for (int m = 0; m < 4; m++) {
                int row = m0 + wm * 64 + m * 16 + lhi * 4;
#pragma unroll
                for (int r = 0; r < 4; r++)
                    Cf[(size_t)(row + r) * N + col] = acc[m][n][r] + bb;
            }
        }
    } else {
#pragma unroll
        for (int n = 0; n < NF; n++) {
            int col = n0 + wn * 16 * NF + n * 16 + llo;
            int third = col >> 10;
            int cl  = col & 1023;
            float bb = bias[col];
            if (third == 2) {
#pragma unroll
                for (int m = 0; m < 4; m++) {
                    int row0 = m0 + wm * 64 + m * 16 + lhi * 4;
                    u16x4 pk;
#pragma unroll
                    for (int r = 0; r < 4; r++) pk[r] = f2bf(acc[m][n][r] + bb);
                    *(u16x4*)&vT[(size_t)cl * M + row0] = pk;
                }
            } else {
                unsigned short* dst = (third == 0) ? kbuf : qbuf;
                const float sc = (third == 1) ? 0.18033688f : 1.0f;  // 0.125*log2e
#pragma unroll
                for (int m = 0; m < 4; m++) {
                    int row0 = m0 + wm * 64 + m * 16 + lhi * 4;
#pragma unroll
                    for (int r = 0; r < 4; r++)
                        dst[(size_t)(row0 + r) * 1024 + cl] = f2bf((acc[m][n][r] + bb) * sc);
                }
            }
        }
    }
}

// ---------------- causal flash attention (R10-exact: log2-domain, gll-staged, swizzled) ----------------
__global__ __launch_bounds__(256, 3) void attn_kernel(
    const unsigned short* __restrict__ K_,
    const unsigned short* __restrict__ Q_,
    const unsigned short* __restrict__ VT_,
    unsigned short* __restrict__ O,
    int S, int H, int M)
{
    const int E = 64 * H;
    const int tid = threadIdx.x;
    const int w = tid >> 6, lane = tid & 63;
    const int llo = lane & 15, lhi = lane >> 4;
    const int id = blockIdx.x;
    const int bh = id & 63;
    const int xi = id >> 6;                 // 0..15, 0 = longest
    const int b = bh >> 4, h = bh & 15;
    const int q0 = (15 - xi) * 128;

    __shared__ __align__(16) unsigned short kvlds[2][2][64 * 64]; // [buf][K/V][row*64+col]
    __shared__ __align__(16) unsigned short Ps[4][32 * 64];       // per-wave, swizzled

    const int qw = q0 + w * 32;

    short8 qf[2][2];
#pragma unroll
    for (int m = 0; m < 2; m++)
#pragma unroll
        for (int kst = 0; kst < 2; kst++)
            qf[m][kst] = *(const short8*)(Q_ + (size_t)(b * S + qw + m * 16 + llo) * E
                                          + h * 64 + kst * 32 + lhi * 8);

    const short one_bf = (short)0x3F80;
    short8 ones = {one_bf, one_bf, one_bf, one_bf, one_bf, one_bf, one_bf, one_bf};

    f32x4 o[2][4];
    f32x4 lac[2];
#pragma unroll
    for (int m = 0; m < 2; m++) {
#pragma unroll
        for (int r = 0; r < 4; r++) lac[m][r] = 0.0f;
#pragma unroll
        for (int df = 0; df < 4; df++)
#pragma unroll
            for (int r = 0; r < 4; r++) o[m][df][r] = 0.0f;
    }

    const int gr = lane >> 3;
    const int gc = ((lane & 7) ^ gr) * 8;   // inverse-swizzled global elem col
    const unsigned short* ksp = K_  + (size_t)(b * S + w * 16 + gr) * E + h * 64 + gc;
    const unsigned short* vsp = VT_ + (size_t)(h * 64 + w * 16 + gr) * M + b * S + gc;
    unsigned short* kd = &kvlds[0][0][w * 16 * 64];
    unsigned short* vd = &kvlds[0][1][w * 16 * 64];

#define STAGE_KV(buf_, kv0_) {                                   \
        const size_t kro = (size_t)(kv0_) * E;                   \
        gll16(ksp + kro,           kd + (buf_) * 2 * 4096);      \
        gll16(ksp + kro + 8 * (size_t)E, kd + (buf_) * 2 * 4096 + 8 * 64); \
        gll16(vsp + (kv0_),        vd + (buf_) * 2 * 4096);      \
        gll16(vsp + (kv0_) + 8 * M, vd + (buf_) * 2 * 4096 + 8 * 64); \
    }

    STAGE_KV(0, 0);

    const int nt = q0 / 64 + 2;
    unsigned short* psw = &Ps[w][0];

    for (int t = 0; t < nt; ++t) {
        const int kv0 = t * 64;
        WAITVM(0);
        __builtin_amdgcn_s_barrier();        // cur landed (all waves); prev reads done
        __builtin_amdgcn_sched_barrier(0);

        if (t + 1 < nt) STAGE_KV((t + 1) & 1, kv0 + 64);

        const unsigned short* kb = &kvlds[t & 1][0][0];
        const unsigned short* vbuf = &kvlds[t & 1][1][0];

        if (kv0 <= qw + 31) {
            // S^T = K Q^T (log2 domain)
            f32x4 st[2][4];
#pragma unroll
            for (int m = 0; m < 2; m++)
#pragma unroll
                for (int nf = 0; nf < 4; nf++)
#pragma unroll
                    for (int r = 0; r < 4; r++) st[m][nf][r] = 0.0f;

#pragma unroll
            for (int kst = 0; kst < 2; kst++) {
                const int pc = ((kst * 4 + lhi) ^ (llo & 7)) * 8;  // swizzled chunk
                short8 kf[4];
#pragma unroll
                for (int nf = 0; nf < 4; nf++)
                    kf[nf] = *(const short8*)&kb[(nf * 16 + llo) * 64 + pc];
#pragma unroll
                for (int m = 0; m < 2; m++)
#pragma unroll
                    for (int nf = 0; nf < 4; nf++)
                        st[m][nf] = __builtin_amdgcn_mfma_f32_16x16x32_bf16(kf[nf], qf[m][kst], st[m][nf], 0, 0, 0);
            }

            const bool need_mask = (kv0 + 63 > qw);
#pragma unroll
            for (int m = 0; m < 2; m++) {
                const int qa = qw + m * 16 + llo;
                if (need_mask) {
#pragma unroll
                    for (int nf = 0; nf < 4; nf++)
#pragma unroll
                        for (int r = 0; r < 4; r++) {
                            int ka = kv0 + nf * 16 + lhi * 4 + r;
                            if (ka > qa) st[m][nf][r] = -1e30f;
                        }
                }
                // P = exp2(S) raw; pack bf16; swizzled 8B store into Ps
#pragma unroll
                for (int nf = 0; nf < 4; nf++) {
                    float p0 = exp2fast(st[m][nf][0]);
                    float p1 = exp2fast(st[m][nf][1]);
                    float p2 = exp2fast(st[m][nf][2]);
                    float p3 = exp2fast(st[m][nf][3]);
                    uint32x2 pk;
                    pk[0] = cvtpk_bf16(p0, p1);
                    pk[1] = cvtpk_bf16(p2, p3);
                    const int p16 = (nf * 2 + (lhi >> 1)) ^ (llo & 7);
                    *(uint32x2*)&psw[(m * 16 + llo) * 64 + p16 * 8 + (lhi & 1) * 4] = pk;
                }
            }

            // O += P V ; l += P·1
#pragma unroll
            for (int kst = 0; kst < 2; kst++) {
                const int pc = ((kst * 4 + lhi) ^ (llo & 7)) * 8;
                short8 pa[2], vb[4];
#pragma unroll
                for (int m = 0; m < 2; m++)
                    pa[m] = *(const short8*)&psw[(m * 16 + llo) * 64 + pc];
#pragma unroll
                for (int df = 0; df < 4; df++)
                    vb[df] = *(const short8*)&vbuf[(df * 16 + llo) * 64 + pc];
#pragma unroll
                for (int m = 0; m < 2; m++) {
#pragma unroll
                    for (int df = 0; df < 4; df++)
                        o[m][df] = __builtin_amdgcn_mfma_f32_16x16x32_bf16(pa[m], vb[df], o[m][df], 0, 0, 0);
                    lac[m] = __builtin_amdgcn_mfma_f32_16x16x32_bf16(pa[m], ones, lac[m], 0, 0, 0);
                }
            }
        }
    }
#undef STAGE_KV

#pragma unroll
    for (int m = 0; m < 2; m++)
#pragma unroll
        for (int r = 0; r < 4; r++) {
            float iv = 1.0f / lac[m][r];
            int q = qw + m * 16 + lhi * 4 + r;
#pragma unroll
            for (int df = 0; df < 4; df++)
                O[(size_t)(b * S + q) * E + h * 64 + df * 16 + llo] = f2bf(o[m][df][r] * iv);
        }
}

extern "C" void kernel_launch(void* const* d_in, const int* in_sizes, int n_in,
                              void* d_out, int out_size, void* d_ws, size_t ws_size,
                              hipStream_t stream) {
    const float* x      = (const float*)d_in[0];
    const float* W_qkv  = (const float*)d_in[1];
    const float* b_qkv  = (const float*)d_in[2];
    const float* W_proj = (const float*)d_in[3];
    const float* b_proj = (const float*)d_in[4];
    float* out = (float*)d_out;

    const int B = 4, S = 2048, E = 1024, H = 16;
    const int M = B * S;  // 8192

    unsigned short* ws     = (unsigned short*)d_ws;
    unsigned short* xb     = ws;                               // [M][E]
    unsigned short* wqkvT  = xb + (size_t)M * E;               // [3E][E]
    unsigned short* wprojT = wqkvT + (size_t)3 * E * E;        // [E][E]
    unsigned short* kbuf   = wprojT + (size_t)E * E;           // [M][E]
    unsigned short* qbuf   = kbuf + (size_t)M * E;             // [M][E]
    unsigned short* vTb    = qbuf + (size_t)M * E;             // [E][M]
    unsigned short* obuf   = vTb + (size_t)M * E;              // [M][E]

    const int nx = M * E;
    prep_kernel<<<dim3(4096 + nx / 1024), 256, 0, stream>>>(x, W_qkv, W_proj, xb, wqkvT, wprojT, nx);

    // QKV: 8-phase 256x256 kernel, grid 12x32 = 384 wgs (1 blk/CU, 128 KiB LDS)
    gemm256<1><<<dim3(3 * E / 256, M / 256), 512, 0, stream>>>(
        xb, wqkvT, b_qkv, nullptr, kbuf, qbuf, vTb, M, 3 * E, E);
    attn_kernel<<<dim3(16 * B * H), 256, 0, stream>>>(kbuf, qbuf, vTb, obuf, S, H, M);
    gemmk64<128, 0, 16><<<dim3(E / 128, M / 128), 512, 0, stream>>>(
        obuf, wprojT, b_proj, out, nullptr, nullptr, nullptr, M, E, E);
}

// Round 2
// 137.799 us; speedup vs baseline: 1.0928x; 1.0928x over previous
//
#include <hip/hip_runtime.h>
#include <hip/hip_bf16.h>

typedef __attribute__((ext_vector_type(8))) short  short8;   // 8 bf16 in 4 VGPRs
typedef __attribute__((ext_vector_type(4))) float  f32x4;
typedef __attribute__((ext_vector_type(4))) unsigned short u16x4;
typedef __attribute__((ext_vector_type(2))) unsigned int  uint32x2;

#define WAITVM(n) asm volatile("s_waitcnt vmcnt(" #n ")" ::: "memory")

__device__ __forceinline__ unsigned short f2bf(float f) {
    union { float f; unsigned int u; } c; c.f = f;
    unsigned int u = c.u + 0x7FFFu + ((c.u >> 16) & 1u);   // RNE
    return (unsigned short)(u >> 16);
}

__device__ __forceinline__ unsigned int cvtpk_bf16(float lo, float hi) {
    unsigned int d;
    asm("v_cvt_pk_bf16_f32 %0, %1, %2" : "=v"(d) : "v"(lo), "v"(hi));
    return d;
}

__device__ __forceinline__ float exp2fast(float x) {
    float r;
    asm("v_exp_f32 %0, %1" : "=v"(r) : "v"(x));
    return r;
}

__device__ __forceinline__ void gll16(const void* g, void* lds) {
    __builtin_amdgcn_global_load_lds(
        (const __attribute__((address_space(1))) unsigned int*)g,
        (__attribute__((address_space(3))) unsigned int*)lds, 16, 0, 0);
}

// ---------------- fused prep: W transposes + x fp32->bf16 convert, one launch ----------------
// Blocks 0..4095: transpose tiles (128 col-tiles x 32 k-tiles); blocks 4096+: cvt x.
__global__ void prep_kernel(const float* __restrict__ x, const float* __restrict__ Wq,
                            const float* __restrict__ Wp, unsigned short* __restrict__ xb,
                            unsigned short* __restrict__ WqT, unsigned short* __restrict__ WpT,
                            int nx) {
    const int blk = blockIdx.x;
    if (blk < 4096) {
        __shared__ float tile[32][33];
        const int cx = blk & 127;          // col-tile: 0..95 Wq, 96..127 Wp
        const int k0 = (blk >> 7) * 32;
        const float* W; unsigned short* Wt; int Nd, n0;
        if (cx < 96) { W = Wq; Wt = WqT; Nd = 3072; n0 = cx * 32; }
        else         { W = Wp; Wt = WpT; Nd = 1024; n0 = (cx - 96) * 32; }
        const int tx = threadIdx.x & 31, ty = threadIdx.x >> 5;   // 32x8
#pragma unroll
        for (int i = 0; i < 4; i++)
            tile[ty + i * 8][tx] = W[(size_t)(k0 + ty + i * 8) * Nd + n0 + tx];
        __syncthreads();
#pragma unroll
        for (int i = 0; i < 4; i++)
            Wt[(size_t)(n0 + ty + i * 8) * 1024 + k0 + tx] = f2bf(tile[tx][ty + i * 8]);
    } else {
        int i = ((blk - 4096) * 256 + threadIdx.x) * 4;
        if (i + 3 >= nx) return;
        float4 v = *(const float4*)(x + i);
        u16x4 o;
        o[0] = f2bf(v.x); o[1] = f2bf(v.y); o[2] = f2bf(v.z); o[3] = f2bf(v.w);
        *(u16x4*)(xb + i) = o;
    }
}

// ---------------- bf16 MFMA GEMM: BM=128, BN in {192,128}, BK=64 (R16-exact) ----------------
// 512 thr = 8 waves (2M x 4N -> wave tile 64 x BN/4). 2-slot LDS ring (80/64 KiB,
// 2 blk/CU), distance-1 prefetch, 1 raw s_barrier + WAITVM(0) per K-step.
// T2 swizzle key=row&7 (conflicts measured 0). ~880 TF on QKV (MfmaUtil 37.5%).
template <int BN, int MODE, int NT>
__global__ __launch_bounds__(512, 4) void gemmk64(
    const unsigned short* __restrict__ A,   // [M][K] bf16
    const unsigned short* __restrict__ Bt,  // [N][K] bf16
    const float* __restrict__ bias,
    float* __restrict__ Cf,
    unsigned short* __restrict__ kbuf,
    unsigned short* __restrict__ qbuf,
    unsigned short* __restrict__ vT,        // [1024][M]
    int M, int N, int K)
{
    constexpr int NF = BN / 64;
    constexpr int ABASE = 128 * 64;
    constexpr int SLOT = (128 + BN) * 64;
    __shared__ __align__(16) unsigned short lds[2][SLOT];

    const int tid = threadIdx.x;
    const int w = tid >> 6, lane = tid & 63;
    const int llo = lane & 15, lhi = lane >> 4;
    const int wm = w >> 2, wn = w & 3;

    const int nwg = gridDim.x * gridDim.y;
    const int bid = blockIdx.y * gridDim.x + blockIdx.x;
    const int wgid = (bid & 7) * (nwg >> 3) + (bid >> 3);
    const int mb = wgid / gridDim.x, nb = wgid - (wgid / gridDim.x) * gridDim.x;
    const int m0 = mb * 128, n0 = nb * BN;

    f32x4 acc[4][NF];
#pragma unroll
    for (int m = 0; m < 4; m++)
#pragma unroll
        for (int n = 0; n < NF; n++)
#pragma unroll
            for (int r = 0; r < 4; r++) acc[m][n][r] = 0.0f;

    const int gr8 = lane >> 3;
    const int swc = ((lane & 7) ^ gr8) * 8;
    const unsigned short* Asrc = A  + (size_t)(m0 + w * 16 + gr8) * K + swc;
    const unsigned short* Bsrc = Bt + (size_t)(n0 + w * 8 * NF + gr8) * K + swc;

    auto STAGE = [&](int sl_, int kt_) {
        unsigned short* sl = &lds[sl_][0];
        const size_t ko = (size_t)kt_ * 64;
        gll16(Asrc + ko,                 sl + (w * 16) * 64);
        gll16(Asrc + ko + 8 * (size_t)K, sl + (w * 16 + 8) * 64);
#pragma unroll
        for (int u = 0; u < NF; u++)
            gll16(Bsrc + ko + (size_t)(8 * u) * K, sl + ABASE + (w * 8 * NF + 8 * u) * 64);
    };

    STAGE(0, 0);

    const int sk = llo & 7;
    const int arow = (wm * 64 + llo) * 64;
    const int brow = ABASE + (wn * 16 * NF + llo) * 64;

    for (int kt = 0; kt < NT; ++kt) {
        WAITVM(0);                             // own tile-kt loads landed
        __builtin_amdgcn_s_barrier();          // all waves: kt published; kt-1 reads done
        __builtin_amdgcn_sched_barrier(0);

        if (kt + 1 < NT) STAGE((kt + 1) & 1, kt + 1);   // into slot read at kt-1

        const unsigned short* sa = &lds[kt & 1][0];

#pragma unroll
        for (int ks = 0; ks < 2; ks++) {
            const int pc = ((ks * 4 + lhi) ^ sk) * 8;
            short8 af[4], bv[NF];
#pragma unroll
            for (int m = 0; m < 4; m++) af[m] = *(const short8*)&sa[arow + m * 1024 + pc];
#pragma unroll
            for (int n = 0; n < NF; n++) bv[n] = *(const short8*)&sa[brow + n * 1024 + pc];

            __builtin_amdgcn_s_setprio(1);
#pragma unroll
            for (int m = 0; m < 4; m++)
#pragma unroll
                for (int n = 0; n < NF; n++)
                    acc[m][n] = __builtin_amdgcn_mfma_f32_16x16x32_bf16(af[m], bv[n], acc[m][n], 0, 0, 0);
            __builtin_amdgcn_s_setprio(0);
        }
    }

    if constexpr (MODE == 0) {
#pragma unroll
        for (int n = 0; n < NF; n++) {
            int col = n0 + wn * 16 * NF + n * 16 + llo;
            float bb = bias[col];
#pragma unroll
            for (int m = 0; m < 4; m++) {
                int row = m0 + wm * 64 + m * 16 + lhi * 4;
#pragma unroll
                for (int r = 0; r < 4; r++)
                    Cf[(size_t)(row + r) * N + col] = acc[m][n][r] + bb;
            }
        }
    } else {
        // QKV split; per-frag third (BN=192 straddles K/Q/V boundaries; frags 16-aligned)
#pragma unroll
        for (int n = 0; n < NF; n++) {
            int col = n0 + wn * 16 * NF + n * 16 + llo;
            int third = col >> 10;
            int cl  = col & 1023;
            float bb = bias[col];
            if (third == 2) {
#pragma unroll
                for (int m = 0; m < 4; m++) {
                    int row0 = m0 + wm * 64 + m * 16 + lhi * 4;
                    u16x4 pk;
#pragma unroll
                    for (int r = 0; r < 4; r++) pk[r] = f2bf(acc[m][n][r] + bb);
                    *(u16x4*)&vT[(size_t)cl * M + row0] = pk;
                }
            } else {
                unsigned short* dst = (third == 0) ? kbuf : qbuf;
                const float sc = (third == 1) ? 0.18033688f : 1.0f;  // 0.125*log2e
#pragma unroll
                for (int m = 0; m < 4; m++) {
                    int row0 = m0 + wm * 64 + m * 16 + lhi * 4;
#pragma unroll
                    for (int r = 0; r < 4; r++)
                        dst[(size_t)(row0 + r) * 1024 + cl] = f2bf((acc[m][n][r] + bb) * sc);
                }
            }
        }
    }
}

// ---------------- causal flash attention (R10-exact: log2-domain, gll-staged, swizzled) ----------------
__global__ __launch_bounds__(256, 3) void attn_kernel(
    const unsigned short* __restrict__ K_,
    const unsigned short* __restrict__ Q_,
    const unsigned short* __restrict__ VT_,
    unsigned short* __restrict__ O,
    int S, int H, int M)
{
    const int E = 64 * H;
    const int tid = threadIdx.x;
    const int w = tid >> 6, lane = tid & 63;
    const int llo = lane & 15, lhi = lane >> 4;
    const int id = blockIdx.x;
    const int bh = id & 63;
    const int xi = id >> 6;                 // 0..15, 0 = longest
    const int b = bh >> 4, h = bh & 15;
    const int q0 = (15 - xi) * 128;

    __shared__ __align__(16) unsigned short kvlds[2][2][64 * 64]; // [buf][K/V][row*64+col]
    __shared__ __align__(16) unsigned short Ps[4][32 * 64];       // per-wave, swizzled

    const int qw = q0 + w * 32;

    short8 qf[2][2];
#pragma unroll
    for (int m = 0; m < 2; m++)
#pragma unroll
        for (int kst = 0; kst < 2; kst++)
            qf[m][kst] = *(const short8*)(Q_ + (size_t)(b * S + qw + m * 16 + llo) * E
                                          + h * 64 + kst * 32 + lhi * 8);

    const short one_bf = (short)0x3F80;
    short8 ones = {one_bf, one_bf, one_bf, one_bf, one_bf, one_bf, one_bf, one_bf};

    f32x4 o[2][4];
    f32x4 lac[2];
#pragma unroll
    for (int m = 0; m < 2; m++) {
#pragma unroll
        for (int r = 0; r < 4; r++) lac[m][r] = 0.0f;
#pragma unroll
        for (int df = 0; df < 4; df++)
#pragma unroll
            for (int r = 0; r < 4; r++) o[m][df][r] = 0.0f;
    }

    const int gr = lane >> 3;
    const int gc = ((lane & 7) ^ gr) * 8;   // inverse-swizzled global elem col
    const unsigned short* ksp = K_  + (size_t)(b * S + w * 16 + gr) * E + h * 64 + gc;
    const unsigned short* vsp = VT_ + (size_t)(h * 64 + w * 16 + gr) * M + b * S + gc;
    unsigned short* kd = &kvlds[0][0][w * 16 * 64];
    unsigned short* vd = &kvlds[0][1][w * 16 * 64];

#define STAGE_KV(buf_, kv0_) {                                   \
        const size_t kro = (size_t)(kv0_) * E;                   \
        gll16(ksp + kro,           kd + (buf_) * 2 * 4096);      \
        gll16(ksp + kro + 8 * (size_t)E, kd + (buf_) * 2 * 4096 + 8 * 64); \
        gll16(vsp + (kv0_),        vd + (buf_) * 2 * 4096);      \
        gll16(vsp + (kv0_) + 8 * M, vd + (buf_) * 2 * 4096 + 8 * 64); \
    }

    STAGE_KV(0, 0);

    const int nt = q0 / 64 + 2;
    unsigned short* psw = &Ps[w][0];

    for (int t = 0; t < nt; ++t) {
        const int kv0 = t * 64;
        WAITVM(0);
        __builtin_amdgcn_s_barrier();        // cur landed (all waves); prev reads done
        __builtin_amdgcn_sched_barrier(0);

        if (t + 1 < nt) STAGE_KV((t + 1) & 1, kv0 + 64);

        const unsigned short* kb = &kvlds[t & 1][0][0];
        const unsigned short* vbuf = &kvlds[t & 1][1][0];

        if (kv0 <= qw + 31) {
            // S^T = K Q^T (log2 domain)
            f32x4 st[2][4];
#pragma unroll
            for (int m = 0; m < 2; m++)
#pragma unroll
                for (int nf = 0; nf < 4; nf++)
#pragma unroll
                    for (int r = 0; r < 4; r++) st[m][nf][r] = 0.0f;

#pragma unroll
            for (int kst = 0; kst < 2; kst++) {
                const int pc = ((kst * 4 + lhi) ^ (llo & 7)) * 8;  // swizzled chunk
                short8 kf[4];
#pragma unroll
                for (int nf = 0; nf < 4; nf++)
                    kf[nf] = *(const short8*)&kb[(nf * 16 + llo) * 64 + pc];
#pragma unroll
                for (int m = 0; m < 2; m++)
#pragma unroll
                    for (int nf = 0; nf < 4; nf++)
                        st[m][nf] = __builtin_amdgcn_mfma_f32_16x16x32_bf16(kf[nf], qf[m][kst], st[m][nf], 0, 0, 0);
            }

            const bool need_mask = (kv0 + 63 > qw);
#pragma unroll
            for (int m = 0; m < 2; m++) {
                const int qa = qw + m * 16 + llo;
                if (need_mask) {
#pragma unroll
                    for (int nf = 0; nf < 4; nf++)
#pragma unroll
                        for (int r = 0; r < 4; r++) {
                            int ka = kv0 + nf * 16 + lhi * 4 + r;
                            if (ka > qa) st[m][nf][r] = -1e30f;
                        }
                }
                // P = exp2(S) raw; pack bf16; swizzled 8B store into Ps
#pragma unroll
                for (int nf = 0; nf < 4; nf++) {
                    float p0 = exp2fast(st[m][nf][0]);
                    float p1 = exp2fast(st[m][nf][1]);
                    float p2 = exp2fast(st[m][nf][2]);
                    float p3 = exp2fast(st[m][nf][3]);
                    uint32x2 pk;
                    pk[0] = cvtpk_bf16(p0, p1);
                    pk[1] = cvtpk_bf16(p2, p3);
                    const int p16 = (nf * 2 + (lhi >> 1)) ^ (llo & 7);
                    *(uint32x2*)&psw[(m * 16 + llo) * 64 + p16 * 8 + (lhi & 1) * 4] = pk;
                }
            }

            // O += P V ; l += P·1
#pragma unroll
            for (int kst = 0; kst < 2; kst++) {
                const int pc = ((kst * 4 + lhi) ^ (llo & 7)) * 8;
                short8 pa[2], vb[4];
#pragma unroll
                for (int m = 0; m < 2; m++)
                    pa[m] = *(const short8*)&psw[(m * 16 + llo) * 64 + pc];
#pragma unroll
                for (int df = 0; df < 4; df++)
                    vb[df] = *(const short8*)&vbuf[(df * 16 + llo) * 64 + pc];
#pragma unroll
                for (int m = 0; m < 2; m++) {
#pragma unroll
                    for (int df = 0; df < 4; df++)
                        o[m][df] = __builtin_amdgcn_mfma_f32_16x16x32_bf16(pa[m], vb[df], o[m][df], 0, 0, 0);
                    lac[m] = __builtin_amdgcn_mfma_f32_16x16x32_bf16(pa[m], ones, lac[m], 0, 0, 0);
                }
            }
        }
    }
#undef STAGE_KV

#pragma unroll
    for (int m = 0; m < 2; m++)
#pragma unroll
        for (int r = 0; r < 4; r++) {
            float iv = 1.0f / lac[m][r];
            int q = qw + m * 16 + lhi * 4 + r;
#pragma unroll
            for (int df = 0; df < 4; df++)
                O[(size_t)(b * S + q) * E + h * 64 + df * 16 + llo] = f2bf(o[m][df][r] * iv);
        }
}

extern "C" void kernel_launch(void* const* d_in, const int* in_sizes, int n_in,
                              void* d_out, int out_size, void* d_ws, size_t ws_size,
                              hipStream_t stream) {
    const float* x      = (const float*)d_in[0];
    const float* W_qkv  = (const float*)d_in[1];
    const float* b_qkv  = (const float*)d_in[2];
    const float* W_proj = (const float*)d_in[3];
    const float* b_proj = (const float*)d_in[4];
    float* out = (float*)d_out;

    const int B = 4, S = 2048, E = 1024, H = 16;
    const int M = B * S;  // 8192

    unsigned short* ws     = (unsigned short*)d_ws;
    unsigned short* xb     = ws;                               // [M][E]
    unsigned short* wqkvT  = xb + (size_t)M * E;               // [3E][E]
    unsigned short* wprojT = wqkvT + (size_t)3 * E * E;        // [E][E]
    unsigned short* kbuf   = wprojT + (size_t)E * E;           // [M][E]
    unsigned short* qbuf   = kbuf + (size_t)M * E;             // [M][E]
    unsigned short* vTb    = qbuf + (size_t)M * E;             // [E][M]
    unsigned short* obuf   = vTb + (size_t)M * E;              // [M][E]

    const int nx = M * E;
    prep_kernel<<<dim3(4096 + nx / 1024), 256, 0, stream>>>(x, W_qkv, W_proj, xb, wqkvT, wprojT, nx);

    gemmk64<192, 1, 16><<<dim3(3 * E / 192, M / 128), 512, 0, stream>>>(
        xb, wqkvT, b_qkv, nullptr, kbuf, qbuf, vTb, M, 3 * E, E);
    attn_kernel<<<dim3(16 * B * H), 256, 0, stream>>>(kbuf, qbuf, vTb, obuf, S, H, M);
    gemmk64<128, 0, 16><<<dim3(E / 128, M / 128), 512, 0, stream>>>(
        obuf, wprojT, b_proj, out, nullptr, nullptr, nullptr, M, E, E);
}